// Round 5
// baseline (303.835 us; speedup 1.0000x reference)
//
#include <hip/hip_runtime.h>
#include <hip/hip_bf16.h>

// out = data @ (mask*weight)^T + bias, via bf16 MFMA.
// Round 5: R4 schedule unchanged (256x256 tile, BK=32, 4-deep LDS ring,
// counted vmcnt, compiler-counted lgkmcnt prefetch, 1 barrier/K-tile);
// MFMA shape switched 16x16x32 -> 32x32x16 (4058 vs 3377 FLOP/cyc/CU).

#define GM 8192
#define GN 4096
#define GK 4096
#define NT (GK / 32)   // 128 K-tiles

typedef __attribute__((ext_vector_type(8))) short short8;
typedef __attribute__((ext_vector_type(8))) short bf16x8;
typedef __attribute__((ext_vector_type(16))) float f32x16;

__device__ __forceinline__ short f2bf(float x) {
    unsigned u = __builtin_bit_cast(unsigned, x);
    u += 0x7fffu + ((u >> 16) & 1u);
    return (short)(u >> 16);
}

__device__ __forceinline__ void stage16(const short* g, short* l) {
    __builtin_amdgcn_global_load_lds(
        (const __attribute__((address_space(1))) unsigned int*)g,
        (__attribute__((address_space(3))) unsigned int*)l, 16, 0, 0);
}

// --- conversion: data f32 -> bf16 ---
__global__ void cvt_data_kernel(const float* __restrict__ in, short* __restrict__ out, long n) {
    long i0 = ((long)blockIdx.x * blockDim.x + threadIdx.x) * 8;
    long stride = (long)gridDim.x * blockDim.x * 8;
    for (long i = i0; i < n; i += stride) {
        float4 a = *(const float4*)(in + i);
        float4 b = *(const float4*)(in + i + 4);
        short8 o;
        o[0] = f2bf(a.x); o[1] = f2bf(a.y); o[2] = f2bf(a.z); o[3] = f2bf(a.w);
        o[4] = f2bf(b.x); o[5] = f2bf(b.y); o[6] = f2bf(b.z); o[7] = f2bf(b.w);
        *(short8*)(out + i) = o;
    }
}

// --- conversion: (mask * weight) f32 -> bf16 ---
__global__ void cvt_w_kernel(const float* __restrict__ w, const float* __restrict__ m,
                             short* __restrict__ out, long n) {
    long i0 = ((long)blockIdx.x * blockDim.x + threadIdx.x) * 8;
    long stride = (long)gridDim.x * blockDim.x * 8;
    for (long i = i0; i < n; i += stride) {
        float4 wa = *(const float4*)(w + i);
        float4 wb = *(const float4*)(w + i + 4);
        float4 ma = *(const float4*)(m + i);
        float4 mb = *(const float4*)(m + i + 4);
        short8 o;
        o[0] = f2bf(wa.x * ma.x); o[1] = f2bf(wa.y * ma.y);
        o[2] = f2bf(wa.z * ma.z); o[3] = f2bf(wa.w * ma.w);
        o[4] = f2bf(wb.x * mb.x); o[5] = f2bf(wb.y * mb.y);
        o[6] = f2bf(wb.z * mb.z); o[7] = f2bf(wb.w * mb.w);
        *(short8*)(out + i) = o;
    }
}

// --- deep-pipelined bf16 NT GEMM, 32x32x16 MFMA ---
// LDS map (shorts): ring r (0..3) at r*16384; A halves at +0,+4096; B at +8192,+12288.
// Half = [128 rows][32 cols] bf16, quarter-swizzled with qx keyed on row bits 1,2:
//   stored quarter = logical quarter ^ ( ((row>>1)&1) | (((row>>2)&1)<<1) )
// Fragment layouts (m74/m101-verified family):
//   A/B operand: lane holds row/col = lane&31, k = (lane>>5)*8 + j
//   C/D: col = lane&31 (N), row = (reg&3) + 8*(reg>>2) + 4*(lane>>5) (M)
//
// Schedule per K-tile T (2 phases, ONE barrier at tile end):
//  p0: stageA(T+3); ds_read AF_P1 <- A m32=2,3 (T); 8 MFMA acc[0..1][*]
//  p1: stageB(T+3); ds_read AF_P0 <- A m32=0,1 (T+1), BF_NXT <- B(T+1);
//      8 MFMA acc[2..3][*]; vmcnt(4); barrier
// Staging invariant identical to R4 (prologue vmcnt(4) => tiles 0,1 landed).
__global__ __launch_bounds__(512, 2) void gemm_8w(const short* __restrict__ A,
                                                  const short* __restrict__ B,
                                                  const float* __restrict__ bias,
                                                  float* __restrict__ C) {
    __shared__ short lds[65536];  // 128 KB

    const int tid  = threadIdx.x;
    const int lane = tid & 63;
    const int wid  = tid >> 6;   // 0..7
    const int wr   = wid >> 2;   // 0..1  (wave row: 128 rows)
    const int wc   = wid & 3;    // 0..3  (wave col: 64 cols)

    // XCD-aware bijective swizzle: nwg = 512, % 8 == 0
    const int bid  = blockIdx.x;
    const int swz  = (bid & 7) * 64 + (bid >> 3);
    const int brow = (swz >> 4) << 8;   // 32 M-tiles
    const int bcol = (swz & 15) << 8;   // 16 N-tiles

    // ---- staging constants (pre-swizzled global source; linear LDS dest) ----
    const int lrow  = tid >> 2;                 // 0..127 row within half
    const int q_log = (tid & 3) ^ (((lrow >> 1) & 1) | (((lrow >> 2) & 1) << 1));
    const size_t aSrc0 = (size_t)(brow + lrow) * GK + q_log * 8;
    const size_t bSrc0 = (size_t)(bcol + lrow) * GK + q_log * 8;

    // ---- fragment-read constants (swizzled LDS read) ----
    const int l31 = lane & 31;
    const int l5  = lane >> 5;                                  // k-octet select
    const int qxl = ((lane >> 1) & 1) | (((lane >> 2) & 1) << 1);
    const int q0  = l5 ^ qxl;                                   // stored quarter, ks=0
    const int aK0 = l31 * 32 + q0 * 8;                          // shorts, within 32-row frag
    const int aK1 = l31 * 32 + (q0 ^ 2) * 8;                    // ks=1: quarter bit1 flips
    const int aBase = wr * 4096;                                // + ring + m32*1024 + aK*
    const int bBase = 8192 + (wc >> 1) * 4096 + (wc & 1) * 2048;  // + ring + n32*1024 + aK*

    f32x16 acc[4][2] = {};
    bf16x8 AF_P0[4], AF_P1[4], BF_A[4], BF_B[4];   // frag idx = m32(or n32)*2 + ks

    auto stageA = [&](int t) {
        const int ring = (t & 3) * 16384;
        const size_t k = (size_t)t * 32;
        #pragma unroll
        for (int h = 0; h < 2; ++h)
            stage16(A + aSrc0 + (size_t)h * 128 * GK + k, &lds[ring + h * 4096 + wid * 512]);
    };
    auto stageB = [&](int t) {
        const int ring = (t & 3) * 16384;
        const size_t k = (size_t)t * 32;
        #pragma unroll
        for (int h = 0; h < 2; ++h)
            stage16(B + bSrc0 + (size_t)h * 128 * GK + k, &lds[ring + 8192 + h * 4096 + wid * 512]);
    };

    // ---- prologue: stage tiles 0,1,2; confirm tiles 0 AND 1 landed ----
    stageA(0); stageB(0);
    stageA(1); stageB(1);
    stageA(2); stageB(2);
    asm volatile("s_waitcnt vmcnt(4)" ::: "memory");  // tiles 0,1 landed
    __builtin_amdgcn_s_barrier();
    asm volatile("" ::: "memory");
    #pragma unroll
    for (int m = 0; m < 2; ++m) {
        AF_P0[m * 2 + 0] = *(const bf16x8*)&lds[aBase + m * 1024 + aK0];
        AF_P0[m * 2 + 1] = *(const bf16x8*)&lds[aBase + m * 1024 + aK1];
    }
    #pragma unroll
    for (int n = 0; n < 2; ++n) {
        BF_A[n * 2 + 0] = *(const bf16x8*)&lds[bBase + n * 1024 + aK0];
        BF_A[n * 2 + 1] = *(const bf16x8*)&lds[bBase + n * 1024 + aK1];
    }

#define TILE_BODY(T, BF_CUR, BF_NXT)                                               \
  {                                                                                 \
    const int ring  = ((T) & 3) * 16384;                                            \
    const int ringN = (((T) + 1) & 3) * 16384;                                      \
    /* ---- phase 0: A m32=2,3 of tile T; MFMA rows 0-63 ---- */                    \
    if ((T) + 3 < NT) stageA((T) + 3);                                              \
    _Pragma("unroll")                                                               \
    for (int m = 0; m < 2; ++m) {                                                   \
      AF_P1[m * 2 + 0] = *(const bf16x8*)&lds[ring + aBase + (m + 2) * 1024 + aK0]; \
      AF_P1[m * 2 + 1] = *(const bf16x8*)&lds[ring + aBase + (m + 2) * 1024 + aK1]; \
    }                                                                               \
    __builtin_amdgcn_sched_barrier(0);                                              \
    __builtin_amdgcn_s_setprio(1);                                                  \
    _Pragma("unroll")                                                               \
    for (int m = 0; m < 2; ++m)                                                     \
      _Pragma("unroll")                                                             \
      for (int n = 0; n < 2; ++n)                                                   \
        _Pragma("unroll")                                                           \
        for (int ks = 0; ks < 2; ++ks)                                              \
          acc[m][n] = __builtin_amdgcn_mfma_f32_32x32x16_bf16(                      \
              AF_P0[m * 2 + ks], BF_CUR[n * 2 + ks], acc[m][n], 0, 0, 0);           \
    __builtin_amdgcn_s_setprio(0);                                                  \
    /* ---- phase 1: prefetch tile T+1 frags; MFMA rows 64-127 ---- */              \
    if ((T) + 3 < NT) stageB((T) + 3);                                              \
    _Pragma("unroll")                                                               \
    for (int m = 0; m < 2; ++m) {                                                   \
      AF_P0[m * 2 + 0] = *(const bf16x8*)&lds[ringN + aBase + m * 1024 + aK0];      \
      AF_P0[m * 2 + 1] = *(const bf16x8*)&lds[ringN + aBase + m * 1024 + aK1];      \
    }                                                                               \
    _Pragma("unroll")                                                               \
    for (int n = 0; n < 2; ++n) {                                                   \
      BF_NXT[n * 2 + 0] = *(const bf16x8*)&lds[ringN + bBase + n * 1024 + aK0];     \
      BF_NXT[n * 2 + 1] = *(const bf16x8*)&lds[ringN + bBase + n * 1024 + aK1];     \
    }                                                                               \
    __builtin_amdgcn_sched_barrier(0);                                              \
    __builtin_amdgcn_s_setprio(1);                                                  \
    _Pragma("unroll")                                                               \
    for (int m = 0; m < 2; ++m)                                                     \
      _Pragma("unroll")                                                             \
      for (int n = 0; n < 2; ++n)                                                   \
        _Pragma("unroll")                                                           \
        for (int ks = 0; ks < 2; ++ks)                                              \
          acc[m + 2][n] = __builtin_amdgcn_mfma_f32_32x32x16_bf16(                  \
              AF_P1[m * 2 + ks], BF_CUR[n * 2 + ks], acc[m + 2][n], 0, 0, 0);       \
    __builtin_amdgcn_s_setprio(0);                                                  \
    if ((T) + 3 < NT) { asm volatile("s_waitcnt vmcnt(4)" ::: "memory"); }          \
    else              { asm volatile("s_waitcnt vmcnt(0)" ::: "memory"); }          \
    __builtin_amdgcn_s_barrier();                                                   \
    asm volatile("" ::: "memory");                                                  \
  }

    for (int T = 0; T < NT; T += 2) {
        TILE_BODY(T,     BF_A, BF_B);   // even tile: B in BF_A, next B -> BF_B
        TILE_BODY(T + 1, BF_B, BF_A);   // odd tile:  B in BF_B, next B -> BF_A
    }
#undef TILE_BODY

    // ---- epilogue: C/D col = lane&31 (N), row = (reg&3)+8*(reg>>2)+4*(lane>>5) ----
    #pragma unroll
    for (int n = 0; n < 2; ++n) {
        const int col = bcol + wc * 64 + n * 32 + l31;
        const float bv = bias[col];
        #pragma unroll
        for (int m = 0; m < 4; ++m) {
            const int rowb = brow + wr * 128 + m * 32 + l5 * 4;
            #pragma unroll
            for (int reg = 0; reg < 16; ++reg) {
                const int row = rowb + (reg & 3) + 8 * (reg >> 2);
                C[(size_t)row * GN + col] = acc[m][n][reg] + bv;
            }
        }
    }
}

extern "C" void kernel_launch(void* const* d_in, const int* in_sizes, int n_in,
                              void* d_out, int out_size, void* d_ws, size_t ws_size,
                              hipStream_t stream) {
    const float* data   = (const float*)d_in[0];  // [8192,4096]
    const float* weight = (const float*)d_in[1];  // [4096,4096]
    const float* mask   = (const float*)d_in[2];  // [4096,4096]
    const float* bias   = (const float*)d_in[3];  // [4096]
    float* out = (float*)d_out;

    short* dataB = (short*)d_ws;                  // 64 MB bf16 data
    short* wB    = dataB + (size_t)GM * GK;       // 32 MB bf16 masked weight

    cvt_data_kernel<<<2048, 256, 0, stream>>>(data, dataB, (long)GM * GK);
    cvt_w_kernel<<<2048, 256, 0, stream>>>(weight, mask, wB, (long)GN * GK);

    // grid = (8192/256) * (4096/256) = 32 * 16 = 512 workgroups, 8 waves each
    gemm_8w<<<512, 512, 0, stream>>>(dataB, wB, bias, out);
}

// Round 6
// 303.638 us; speedup vs baseline: 1.0006x; 1.0006x over previous
//
#include <hip/hip_runtime.h>
#include <hip/hip_bf16.h>

// out = data @ (mask*weight)^T + bias, via bf16 MFMA.
// Round 6: R5 (32x32x16 MFMA, 256x256 tile, BK=32, ring-4, counted vmcnt,
// 1 barrier/K-tile) with the quarter-swizzle re-keyed on row bits {1,3}
// (R4's measured-zero-conflict key) instead of {1,2} (R5: 2.5e7 conflicts).

#define GM 8192
#define GN 4096
#define GK 4096
#define NT (GK / 32)   // 128 K-tiles

typedef __attribute__((ext_vector_type(8))) short short8;
typedef __attribute__((ext_vector_type(8))) short bf16x8;
typedef __attribute__((ext_vector_type(16))) float f32x16;

__device__ __forceinline__ short f2bf(float x) {
    unsigned u = __builtin_bit_cast(unsigned, x);
    u += 0x7fffu + ((u >> 16) & 1u);
    return (short)(u >> 16);
}

__device__ __forceinline__ void stage16(const short* g, short* l) {
    __builtin_amdgcn_global_load_lds(
        (const __attribute__((address_space(1))) unsigned int*)g,
        (__attribute__((address_space(3))) unsigned int*)l, 16, 0, 0);
}

// --- conversion: data f32 -> bf16 ---
__global__ void cvt_data_kernel(const float* __restrict__ in, short* __restrict__ out, long n) {
    long i0 = ((long)blockIdx.x * blockDim.x + threadIdx.x) * 8;
    long stride = (long)gridDim.x * blockDim.x * 8;
    for (long i = i0; i < n; i += stride) {
        float4 a = *(const float4*)(in + i);
        float4 b = *(const float4*)(in + i + 4);
        short8 o;
        o[0] = f2bf(a.x); o[1] = f2bf(a.y); o[2] = f2bf(a.z); o[3] = f2bf(a.w);
        o[4] = f2bf(b.x); o[5] = f2bf(b.y); o[6] = f2bf(b.z); o[7] = f2bf(b.w);
        *(short8*)(out + i) = o;
    }
}

// --- conversion: (mask * weight) f32 -> bf16 ---
__global__ void cvt_w_kernel(const float* __restrict__ w, const float* __restrict__ m,
                             short* __restrict__ out, long n) {
    long i0 = ((long)blockIdx.x * blockDim.x + threadIdx.x) * 8;
    long stride = (long)gridDim.x * blockDim.x * 8;
    for (long i = i0; i < n; i += stride) {
        float4 wa = *(const float4*)(w + i);
        float4 wb = *(const float4*)(w + i + 4);
        float4 ma = *(const float4*)(m + i);
        float4 mb = *(const float4*)(m + i + 4);
        short8 o;
        o[0] = f2bf(wa.x * ma.x); o[1] = f2bf(wa.y * ma.y);
        o[2] = f2bf(wa.z * ma.z); o[3] = f2bf(wa.w * ma.w);
        o[4] = f2bf(wb.x * mb.x); o[5] = f2bf(wb.y * mb.y);
        o[6] = f2bf(wb.z * mb.z); o[7] = f2bf(wb.w * mb.w);
        *(short8*)(out + i) = o;
    }
}

// --- deep-pipelined bf16 NT GEMM, 32x32x16 MFMA ---
// LDS map (shorts): ring r (0..3) at r*16384; A halves at +0,+4096; B at +8192,+12288.
// Half = [128 rows][32 cols] bf16, quarter-swizzled with key on row bits {1,3}:
//   stored quarter = logical quarter ^ ( ((row>>1)&1) | (((row>>3)&1)<<1) )
// (R4's zero-conflict key; all fragment row offsets are multiples of 32 so
// row bits 1,3 come straight from lane bits 1,3 on the read side.)
// Fragment layouts (m74/m101-verified family):
//   A/B operand: lane holds row/col = lane&31, k = (lane>>5)*8 + j
//   C/D: col = lane&31 (N), row = (reg&3) + 8*(reg>>2) + 4*(lane>>5) (M)
//
// Schedule per K-tile T (2 phases, ONE barrier at tile end):
//  p0: stageA(T+3); ds_read AF_P1 <- A m32=2,3 (T); 8 MFMA acc[0..1][*]
//  p1: stageB(T+3); ds_read AF_P0 <- A m32=0,1 (T+1), BF_NXT <- B(T+1);
//      8 MFMA acc[2..3][*]; vmcnt(4); barrier
// Staging invariant identical to R4/R5 (prologue vmcnt(4) => tiles 0,1 landed).
__global__ __launch_bounds__(512, 2) void gemm_8w(const short* __restrict__ A,
                                                  const short* __restrict__ B,
                                                  const float* __restrict__ bias,
                                                  float* __restrict__ C) {
    __shared__ short lds[65536];  // 128 KB

    const int tid  = threadIdx.x;
    const int lane = tid & 63;
    const int wid  = tid >> 6;   // 0..7
    const int wr   = wid >> 2;   // 0..1  (wave row: 128 rows)
    const int wc   = wid & 3;    // 0..3  (wave col: 64 cols)

    // XCD-aware bijective swizzle: nwg = 512, % 8 == 0
    const int bid  = blockIdx.x;
    const int swz  = (bid & 7) * 64 + (bid >> 3);
    const int brow = (swz >> 4) << 8;   // 32 M-tiles
    const int bcol = (swz & 15) << 8;   // 16 N-tiles

    // ---- staging constants (pre-swizzled global source; linear LDS dest) ----
    const int lrow  = tid >> 2;                 // 0..127 row within half
    const int q_log = (tid & 3) ^ (((lrow >> 1) & 1) | (((lrow >> 3) & 1) << 1));  // key {1,3}
    const size_t aSrc0 = (size_t)(brow + lrow) * GK + q_log * 8;
    const size_t bSrc0 = (size_t)(bcol + lrow) * GK + q_log * 8;

    // ---- fragment-read constants (swizzled LDS read) ----
    const int l31 = lane & 31;
    const int l5  = lane >> 5;                                  // k-octet select
    const int qxl = ((lane >> 1) & 1) | (((lane >> 3) & 1) << 1);  // key {1,3}
    const int q0  = l5 ^ qxl;                                   // stored quarter, ks=0
    const int aK0 = l31 * 32 + q0 * 8;                          // shorts, within 32-row frag
    const int aK1 = l31 * 32 + (q0 ^ 2) * 8;                    // ks=1: quarter bit1 flips
    const int aBase = wr * 4096;                                // + ring + m32*1024 + aK*
    const int bBase = 8192 + (wc >> 1) * 4096 + (wc & 1) * 2048;  // + ring + n32*1024 + aK*

    f32x16 acc[4][2] = {};
    bf16x8 AF_P0[4], AF_P1[4], BF_A[4], BF_B[4];   // frag idx = m32(or n32)*2 + ks

    auto stageA = [&](int t) {
        const int ring = (t & 3) * 16384;
        const size_t k = (size_t)t * 32;
        #pragma unroll
        for (int h = 0; h < 2; ++h)
            stage16(A + aSrc0 + (size_t)h * 128 * GK + k, &lds[ring + h * 4096 + wid * 512]);
    };
    auto stageB = [&](int t) {
        const int ring = (t & 3) * 16384;
        const size_t k = (size_t)t * 32;
        #pragma unroll
        for (int h = 0; h < 2; ++h)
            stage16(B + bSrc0 + (size_t)h * 128 * GK + k, &lds[ring + 8192 + h * 4096 + wid * 512]);
    };

    // ---- prologue: stage tiles 0,1,2; confirm tiles 0 AND 1 landed ----
    stageA(0); stageB(0);
    stageA(1); stageB(1);
    stageA(2); stageB(2);
    asm volatile("s_waitcnt vmcnt(4)" ::: "memory");  // tiles 0,1 landed
    __builtin_amdgcn_s_barrier();
    asm volatile("" ::: "memory");
    #pragma unroll
    for (int m = 0; m < 2; ++m) {
        AF_P0[m * 2 + 0] = *(const bf16x8*)&lds[aBase + m * 1024 + aK0];
        AF_P0[m * 2 + 1] = *(const bf16x8*)&lds[aBase + m * 1024 + aK1];
    }
    #pragma unroll
    for (int n = 0; n < 2; ++n) {
        BF_A[n * 2 + 0] = *(const bf16x8*)&lds[bBase + n * 1024 + aK0];
        BF_A[n * 2 + 1] = *(const bf16x8*)&lds[bBase + n * 1024 + aK1];
    }

#define TILE_BODY(T, BF_CUR, BF_NXT)                                               \
  {                                                                                 \
    const int ring  = ((T) & 3) * 16384;                                            \
    const int ringN = (((T) + 1) & 3) * 16384;                                      \
    /* ---- phase 0: A m32=2,3 of tile T; MFMA rows 0-63 ---- */                    \
    if ((T) + 3 < NT) stageA((T) + 3);                                              \
    _Pragma("unroll")                                                               \
    for (int m = 0; m < 2; ++m) {                                                   \
      AF_P1[m * 2 + 0] = *(const bf16x8*)&lds[ring + aBase + (m + 2) * 1024 + aK0]; \
      AF_P1[m * 2 + 1] = *(const bf16x8*)&lds[ring + aBase + (m + 2) * 1024 + aK1]; \
    }                                                                               \
    __builtin_amdgcn_sched_barrier(0);                                              \
    __builtin_amdgcn_s_setprio(1);                                                  \
    _Pragma("unroll")                                                               \
    for (int m = 0; m < 2; ++m)                                                     \
      _Pragma("unroll")                                                             \
      for (int n = 0; n < 2; ++n)                                                   \
        _Pragma("unroll")                                                           \
        for (int ks = 0; ks < 2; ++ks)                                              \
          acc[m][n] = __builtin_amdgcn_mfma_f32_32x32x16_bf16(                      \
              AF_P0[m * 2 + ks], BF_CUR[n * 2 + ks], acc[m][n], 0, 0, 0);           \
    __builtin_amdgcn_s_setprio(0);                                                  \
    /* ---- phase 1: prefetch tile T+1 frags; MFMA rows 64-127 ---- */              \
    if ((T) + 3 < NT) stageB((T) + 3);                                              \
    _Pragma("unroll")                                                               \
    for (int m = 0; m < 2; ++m) {                                                   \
      AF_P0[m * 2 + 0] = *(const bf16x8*)&lds[ringN + aBase + m * 1024 + aK0];      \
      AF_P0[m * 2 + 1] = *(const bf16x8*)&lds[ringN + aBase + m * 1024 + aK1];      \
    }                                                                               \
    _Pragma("unroll")                                                               \
    for (int n = 0; n < 2; ++n) {                                                   \
      BF_NXT[n * 2 + 0] = *(const bf16x8*)&lds[ringN + bBase + n * 1024 + aK0];     \
      BF_NXT[n * 2 + 1] = *(const bf16x8*)&lds[ringN + bBase + n * 1024 + aK1];     \
    }                                                                               \
    __builtin_amdgcn_sched_barrier(0);                                              \
    __builtin_amdgcn_s_setprio(1);                                                  \
    _Pragma("unroll")                                                               \
    for (int m = 0; m < 2; ++m)                                                     \
      _Pragma("unroll")                                                             \
      for (int n = 0; n < 2; ++n)                                                   \
        _Pragma("unroll")                                                           \
        for (int ks = 0; ks < 2; ++ks)                                              \
          acc[m + 2][n] = __builtin_amdgcn_mfma_f32_32x32x16_bf16(                  \
              AF_P1[m * 2 + ks], BF_CUR[n * 2 + ks], acc[m + 2][n], 0, 0, 0);       \
    __builtin_amdgcn_s_setprio(0);                                                  \
    if ((T) + 3 < NT) { asm volatile("s_waitcnt vmcnt(4)" ::: "memory"); }          \
    else              { asm volatile("s_waitcnt vmcnt(0)" ::: "memory"); }          \
    __builtin_amdgcn_s_barrier();                                                   \
    asm volatile("" ::: "memory");                                                  \
  }

    for (int T = 0; T < NT; T += 2) {
        TILE_BODY(T,     BF_A, BF_B);   // even tile: B in BF_A, next B -> BF_B
        TILE_BODY(T + 1, BF_B, BF_A);   // odd tile:  B in BF_B, next B -> BF_A
    }
#undef TILE_BODY

    // ---- epilogue: C/D col = lane&31 (N), row = (reg&3)+8*(reg>>2)+4*(lane>>5) ----
    #pragma unroll
    for (int n = 0; n < 2; ++n) {
        const int col = bcol + wc * 64 + n * 32 + l31;
        const float bv = bias[col];
        #pragma unroll
        for (int m = 0; m < 4; ++m) {
            const int rowb = brow + wr * 128 + m * 32 + l5 * 4;
            #pragma unroll
            for (int reg = 0; reg < 16; ++reg) {
                const int row = rowb + (reg & 3) + 8 * (reg >> 2);
                C[(size_t)row * GN + col] = acc[m][n][reg] + bv;
            }
        }
    }
}

extern "C" void kernel_launch(void* const* d_in, const int* in_sizes, int n_in,
                              void* d_out, int out_size, void* d_ws, size_t ws_size,
                              hipStream_t stream) {
    const float* data   = (const float*)d_in[0];  // [8192,4096]
    const float* weight = (const float*)d_in[1];  // [4096,4096]
    const float* mask   = (const float*)d_in[2];  // [4096,4096]
    const float* bias   = (const float*)d_in[3];  // [4096]
    float* out = (float*)d_out;

    short* dataB = (short*)d_ws;                  // 64 MB bf16 data
    short* wB    = dataB + (size_t)GM * GK;       // 32 MB bf16 masked weight

    cvt_data_kernel<<<2048, 256, 0, stream>>>(data, dataB, (long)GM * GK);
    cvt_w_kernel<<<2048, 256, 0, stream>>>(weight, mask, wB, (long)GN * GK);

    // grid = (8192/256) * (4096/256) = 32 * 16 = 512 workgroups, 8 waves each
    gemm_8w<<<512, 512, 0, stream>>>(dataB, wB, bias, out);
}

// Round 7
// 298.201 us; speedup vs baseline: 1.0189x; 1.0182x over previous
//
#include <hip/hip_runtime.h>
#include <hip/hip_bf16.h>

// out = data @ (mask*weight)^T + bias, via bf16 MFMA.
// Round 7: m201-style 8-phase schedule on R4's proven-zero-conflict LDS
// geometry. BK=64 as TWO 32-col blocks (each [256r][32c], 64B rows, R4
// quarter-swizzle), dbuf-2, 4 phases/K-tile, counted vmcnt(2), 16x16x32 MFMA.

#define GM 8192
#define GN 4096
#define GK 4096
#define NT (GK / 64)   // 64 K-tiles of BK=64

typedef __attribute__((ext_vector_type(8))) short short8;
typedef __attribute__((ext_vector_type(8))) short bf16x8;
typedef __attribute__((ext_vector_type(4))) float f32x4;

__device__ __forceinline__ short f2bf(float x) {
    unsigned u = __builtin_bit_cast(unsigned, x);
    u += 0x7fffu + ((u >> 16) & 1u);
    return (short)(u >> 16);
}

__device__ __forceinline__ void stage16(const short* g, short* l) {
    __builtin_amdgcn_global_load_lds(
        (const __attribute__((address_space(1))) unsigned int*)g,
        (__attribute__((address_space(3))) unsigned int*)l, 16, 0, 0);
}

// --- conversion: data f32 -> bf16 ---
__global__ void cvt_data_kernel(const float* __restrict__ in, short* __restrict__ out, long n) {
    long i0 = ((long)blockIdx.x * blockDim.x + threadIdx.x) * 8;
    long stride = (long)gridDim.x * blockDim.x * 8;
    for (long i = i0; i < n; i += stride) {
        float4 a = *(const float4*)(in + i);
        float4 b = *(const float4*)(in + i + 4);
        short8 o;
        o[0] = f2bf(a.x); o[1] = f2bf(a.y); o[2] = f2bf(a.z); o[3] = f2bf(a.w);
        o[4] = f2bf(b.x); o[5] = f2bf(b.y); o[6] = f2bf(b.z); o[7] = f2bf(b.w);
        *(short8*)(out + i) = o;
    }
}

// --- conversion: (mask * weight) f32 -> bf16 ---
__global__ void cvt_w_kernel(const float* __restrict__ w, const float* __restrict__ m,
                             short* __restrict__ out, long n) {
    long i0 = ((long)blockIdx.x * blockDim.x + threadIdx.x) * 8;
    long stride = (long)gridDim.x * blockDim.x * 8;
    for (long i = i0; i < n; i += stride) {
        float4 wa = *(const float4*)(w + i);
        float4 wb = *(const float4*)(w + i + 4);
        float4 ma = *(const float4*)(m + i);
        float4 mb = *(const float4*)(m + i + 4);
        short8 o;
        o[0] = f2bf(wa.x * ma.x); o[1] = f2bf(wa.y * ma.y);
        o[2] = f2bf(wa.z * ma.z); o[3] = f2bf(wa.w * ma.w);
        o[4] = f2bf(wb.x * mb.x); o[5] = f2bf(wb.y * mb.y);
        o[6] = f2bf(wb.z * mb.z); o[7] = f2bf(wb.w * mb.w);
        *(short8*)(out + i) = o;
    }
}

// --- 8-phase deep-pipelined bf16 NT GEMM ---
// LDS (shorts): dbuf d at d*32768. Within dbuf: A kb0 +0, A kb1 +8192,
//   B kb0 +16384, B kb1 +24576. Block = [256 rows][32 cols] bf16, 64B rows,
//   quarter-swizzled: stored q = logical q ^ ((((row>>3)&1)<<1) | ((row>>1)&1))
//   == R4's measured-zero-conflict geometry, byte-for-byte on every ds_read.
//
// Per K-tile T: 4 phases (kb*2+mh). Phase = {vmcnt?; ds_read frags (4 or 8
// b128); stage one unit of T+1 (2 loads); barrier; lgkmcnt(0)+sched_barrier;
// setprio(1); 16 MFMA; setprio(0); barrier}.
// Stage units: U0=A.kb0@p0, U1=B.kb0@p1, U2=A.kb1@p2, U3=B.kb1@p3.
// vmcnt(2) at p1 confirms through U3(T)  -> U2,U3(T) safe for p2 (barrier-crossed).
// vmcnt(2) at p3 confirms through U1(T+1)-> U0,U1(T+1) safe for next p0.
// Prologue: 8 loads + vmcnt(4) confirms U0,U1(tile0). Last tile: vmcnt(0).
__global__ __launch_bounds__(512, 2) void gemm_8w(const short* __restrict__ A,
                                                  const short* __restrict__ B,
                                                  const float* __restrict__ bias,
                                                  float* __restrict__ C) {
    __shared__ short lds[65536];  // 128 KB

    const int tid  = threadIdx.x;
    const int lane = tid & 63;
    const int wid  = tid >> 6;   // 0..7
    const int wr   = wid >> 2;   // 0..1  (wave row: 128 rows)
    const int wc   = wid & 3;    // 0..3  (wave col: 64 cols)

    // XCD-aware bijective swizzle: nwg = 512, % 8 == 0
    const int bid  = blockIdx.x;
    const int swz  = (bid & 7) * 64 + (bid >> 3);
    const int brow = (swz >> 4) << 8;   // 32 M-tiles
    const int bcol = (swz & 15) << 8;   // 16 N-tiles

    // ---- staging constants (pre-swizzled global source; linear LDS dest) ----
    const int trow = tid >> 2;          // row within 128-row chunk
    const int qlog = (tid & 3) ^ ((((trow >> 3) & 1) << 1) | ((trow >> 1) & 1));

    // ---- fragment-read constants (R4's swizzled read) ----
    const int l15 = lane & 15;
    const int q   = lane >> 4;
    const int qx  = (((l15 >> 3) & 1) << 1) | ((l15 >> 1) & 1);
    const int foff = l15 * 32 + ((q ^ qx) << 3);   // shorts, within block
    const int aW = wr * 4096;                       // + dbuf + kb*8192 + m*512
    const int bW = wc * 2048;                       // + dbuf + 16384 + kb*8192 + n*512

    f32x4 acc[8][4] = {};
    bf16x8 af[4], bfr[4];

    auto stA = [&](int kb, int sb, size_t kcol) {
        #pragma unroll
        for (int j = 0; j < 2; ++j)
            stage16(A + (size_t)(brow + j * 128 + trow) * GK + kcol + kb * 32 + qlog * 8,
                    &lds[sb + kb * 8192 + j * 4096 + wid * 512]);
    };
    auto stB = [&](int kb, int sb, size_t kcol) {
        #pragma unroll
        for (int j = 0; j < 2; ++j)
            stage16(B + (size_t)(bcol + j * 128 + trow) * GK + kcol + kb * 32 + qlog * 8,
                    &lds[sb + 16384 + kb * 8192 + j * 4096 + wid * 512]);
    };

    // ---- prologue: stage tile 0 (units U0..U3), confirm U0,U1 ----
    stA(0, 0, 0); stB(0, 0, 0); stA(1, 0, 0); stB(1, 0, 0);
    asm volatile("s_waitcnt vmcnt(4)" ::: "memory");
    __builtin_amdgcn_s_barrier();
    asm volatile("" ::: "memory");

#define PHASE(KB, MH, VMSTMT, STGSTMT)                                            \
  {                                                                                \
    VMSTMT;                                                                        \
    _Pragma("unroll")                                                              \
    for (int m = 0; m < 4; ++m)                                                    \
      af[m] = *(const bf16x8*)&lds[cb + (KB) * 8192 + aW + ((MH) * 4 + m) * 512 + foff]; \
    if ((MH) == 0) {                                                               \
      _Pragma("unroll")                                                            \
      for (int n = 0; n < 4; ++n)                                                  \
        bfr[n] = *(const bf16x8*)&lds[cb + 16384 + (KB) * 8192 + bW + n * 512 + foff]; \
    }                                                                              \
    STGSTMT;                                                                       \
    __builtin_amdgcn_s_barrier();                                                  \
    asm volatile("s_waitcnt lgkmcnt(0)" ::: "memory");                             \
    __builtin_amdgcn_sched_barrier(0);                                             \
    __builtin_amdgcn_s_setprio(1);                                                 \
    _Pragma("unroll")                                                              \
    for (int m = 0; m < 4; ++m)                                                    \
      _Pragma("unroll")                                                            \
      for (int n = 0; n < 4; ++n)                                                  \
        acc[(MH) * 4 + m][n] = __builtin_amdgcn_mfma_f32_16x16x32_bf16(            \
            af[m], bfr[n], acc[(MH) * 4 + m][n], 0, 0, 0);                         \
    __builtin_amdgcn_s_setprio(0);                                                 \
    __builtin_amdgcn_s_barrier();                                                  \
    asm volatile("" ::: "memory");                                                 \
  }

    for (int T = 0; T < NT; ++T) {
        const int cb = (T & 1) << 15;        // compute dbuf base (shorts)
        const int sb = 32768 - cb;           // stage dbuf base
        const size_t kn = (size_t)(T + 1) * 64;
        const bool st = (T + 1 < NT);

        PHASE(0, 0, , if (st) stA(0, sb, kn))
        PHASE(0, 1,
              if (st) { asm volatile("s_waitcnt vmcnt(2)" ::: "memory"); }
              else    { asm volatile("s_waitcnt vmcnt(0)" ::: "memory"); },
              if (st) stB(0, sb, kn))
        PHASE(1, 0, , if (st) stA(1, sb, kn))
        PHASE(1, 1,
              if (st) { asm volatile("s_waitcnt vmcnt(2)" ::: "memory"); }
              else    { asm volatile("s_waitcnt vmcnt(0)" ::: "memory"); },
              if (st) stB(1, sb, kn))
    }
#undef PHASE

    // ---- epilogue: C/D layout col = lane&15, row = (lane>>4)*4 + r ----
    #pragma unroll
    for (int n = 0; n < 4; ++n) {
        const int col = bcol + wc * 64 + n * 16 + l15;
        const float bv = bias[col];
        #pragma unroll
        for (int m = 0; m < 8; ++m) {
            const int rowb = brow + wr * 128 + m * 16 + (q << 2);
            #pragma unroll
            for (int r = 0; r < 4; ++r)
                C[(size_t)(rowb + r) * GN + col] = acc[m][n][r] + bv;
        }
    }
}

extern "C" void kernel_launch(void* const* d_in, const int* in_sizes, int n_in,
                              void* d_out, int out_size, void* d_ws, size_t ws_size,
                              hipStream_t stream) {
    const float* data   = (const float*)d_in[0];  // [8192,4096]
    const float* weight = (const float*)d_in[1];  // [4096,4096]
    const float* mask   = (const float*)d_in[2];  // [4096,4096]
    const float* bias   = (const float*)d_in[3];  // [4096]
    float* out = (float*)d_out;

    short* dataB = (short*)d_ws;                  // 64 MB bf16 data
    short* wB    = dataB + (size_t)GM * GK;       // 32 MB bf16 masked weight

    cvt_data_kernel<<<2048, 256, 0, stream>>>(data, dataB, (long)GM * GK);
    cvt_w_kernel<<<2048, 256, 0, stream>>>(weight, mask, wB, (long)GN * GK);

    // grid = (8192/256) * (4096/256) = 32 * 16 = 512 workgroups, 8 waves each
    gemm_8w<<<512, 512, 0, stream>>>(dataB, wB, bias, out);
}